// Round 1
// baseline (544.275 us; speedup 1.0000x reference)
//
#include <hip/hip_runtime.h>

#define BB 64
#define NN 128
#define BN 8192
#define EE 262144
#define HIDD 128
#define NRBF 64
#define NBLK 4
#define TLUT 1024
#define CAP 128
#define RCUTF 6.0f
#define GAMMAF (10.0f / 36.0f)

__device__ __forceinline__ float silu_f(float v) {
    return v / (1.0f + __expf(-v));
}

// h[a][f] = embed_w[Z[a]][f]
__global__ void k_embed(const int* __restrict__ Z, const float* __restrict__ ew,
                        float* __restrict__ h) {
    int i = blockIdx.x * 256 + threadIdx.x;   // over BN*HIDD
    int a = i >> 7, f = i & 127;
    h[i] = ew[Z[a] * HIDD + f];
}

// bucket edges by dst; store (src, clamped distance)
__global__ void k_edges(const int* __restrict__ ei, const float* __restrict__ pos,
                        int* __restrict__ cnt, int* __restrict__ bsrc,
                        float* __restrict__ bd) {
    int e = blockIdx.x * 256 + threadIdx.x;
    int s = ei[e];
    int d = ei[EE + e];
    float dx = pos[s * 3 + 0] - pos[d * 3 + 0];
    float dy = pos[s * 3 + 1] - pos[d * 3 + 1];
    float dz = pos[s * 3 + 2] - pos[d * 3 + 2];
    float dist = sqrtf(dx * dx + dy * dy + dz * dz);
    dist = fminf(dist, RCUTF);
    int p = atomicAdd(&cnt[d], 1);
    if (p < CAP) {
        bsrc[d * CAP + p] = s;
        bd[d * CAP + p] = dist;
    }
}

// RBF feature matrix for the LUT grid: R[t][k] = exp(-gamma*(d_t - c_k)^2)
__global__ void k_rbf(float* __restrict__ R) {
    int i = blockIdx.x * 256 + threadIdx.x;   // TLUT*NRBF
    int t = i >> 6, k = i & 63;
    float d = t * (RCUTF / (TLUT - 1));
    float c = k * (RCUTF / 63.0f);
    float u = d - c;
    R[i] = __expf(-GAMMAF * u * u);
}

// C[M,128] = act(A[M,K] @ W[K,128] + bias). M multiple of 32, K in {64,128}.
__global__ __launch_bounds__(256) void k_gemm(const float* __restrict__ A,
                                              const float* __restrict__ W,
                                              const float* __restrict__ bias,
                                              float* __restrict__ C, int K, int act) {
    __shared__ float As[32][32];
    __shared__ float Ws[32][128];
    int tid = threadIdx.x;
    int tx = tid & 31, ty = tid >> 5;
    int c0 = tx * 4;
    int rr = ty * 4;
    int r0 = blockIdx.x * 32;
    float acc[4][4] = {};
    for (int kc = 0; kc < K; kc += 32) {
        // stage A chunk 32x32
        int lr = tid >> 3, lc = (tid & 7) * 4;
        float4 av = *(const float4*)&A[(size_t)(r0 + lr) * K + kc + lc];
        *(float4*)&As[lr][lc] = av;
        // stage W chunk 32x128
#pragma unroll
        for (int j = 0; j < 4; ++j) {
            int idx = tid + j * 256;
            int wr = idx >> 5, wc = (idx & 31) * 4;
            float4 wv = *(const float4*)&W[(size_t)(kc + wr) * HIDD + wc];
            *(float4*)&Ws[wr][wc] = wv;
        }
        __syncthreads();
#pragma unroll 8
        for (int k = 0; k < 32; ++k) {
            float4 wv = *(float4*)&Ws[k][c0];
            float a0 = As[rr + 0][k], a1 = As[rr + 1][k];
            float a2 = As[rr + 2][k], a3 = As[rr + 3][k];
            acc[0][0] += a0 * wv.x; acc[0][1] += a0 * wv.y; acc[0][2] += a0 * wv.z; acc[0][3] += a0 * wv.w;
            acc[1][0] += a1 * wv.x; acc[1][1] += a1 * wv.y; acc[1][2] += a1 * wv.z; acc[1][3] += a1 * wv.w;
            acc[2][0] += a2 * wv.x; acc[2][1] += a2 * wv.y; acc[2][2] += a2 * wv.z; acc[2][3] += a2 * wv.w;
            acc[3][0] += a3 * wv.x; acc[3][1] += a3 * wv.y; acc[3][2] += a3 * wv.z; acc[3][3] += a3 * wv.w;
        }
        __syncthreads();
    }
#pragma unroll
    for (int i = 0; i < 4; ++i) {
        float4 o;
        o.x = acc[i][0]; o.y = acc[i][1]; o.z = acc[i][2]; o.w = acc[i][3];
        if (bias) {
            o.x += bias[c0 + 0]; o.y += bias[c0 + 1];
            o.z += bias[c0 + 2]; o.w += bias[c0 + 3];
        }
        if (act) {
            o.x = silu_f(o.x); o.y = silu_f(o.y);
            o.z = silu_f(o.z); o.w = silu_f(o.w);
        }
        *(float4*)&C[(size_t)(r0 + rr + i) * HIDD + c0] = o;
    }
}

// one wave per dst atom: agg[dst][:] = sum_e w(d_e) * x[src_e][:]
__global__ __launch_bounds__(256) void k_agg(const int* __restrict__ cnt,
                                             const int* __restrict__ bsrc,
                                             const float* __restrict__ bd,
                                             const float* __restrict__ lut,
                                             const float* __restrict__ x,
                                             float* __restrict__ agg) {
    int dst = blockIdx.x * 4 + (threadIdx.x >> 6);
    int lane = threadIdx.x & 63;
    int n = cnt[dst];
    n = n > CAP ? CAP : n;
    const float2* lut2 = (const float2*)lut;
    const float2* x2 = (const float2*)x;
    float ax = 0.0f, ay = 0.0f;
    for (int t = 0; t < n; ++t) {
        int s = bsrc[dst * CAP + t];
        float dd = bd[dst * CAP + t];
        float f = dd * ((TLUT - 1) / RCUTF);
        int i0 = (int)f;
        i0 = i0 > TLUT - 2 ? TLUT - 2 : i0;
        float fr = f - (float)i0;
        float2 l0 = lut2[i0 * 64 + lane];
        float2 l1 = lut2[(i0 + 1) * 64 + lane];
        float2 xv = x2[(size_t)s * 64 + lane];
        float wx = l0.x + fr * (l1.x - l0.x);
        float wy = l0.y + fr * (l1.y - l0.y);
        ax += wx * xv.x;
        ay += wy * xv.y;
    }
    float2 o; o.x = ax; o.y = ay;
    ((float2*)agg)[(size_t)dst * 64 + lane] = o;
}

// h = LayerNorm(h + t2) * g + b, one wave per row
__global__ __launch_bounds__(256) void k_ln(float* __restrict__ h,
                                            const float* __restrict__ t2,
                                            const float* __restrict__ g,
                                            const float* __restrict__ b) {
    int row = blockIdx.x * 4 + (threadIdx.x >> 6);
    int lane = threadIdx.x & 63;
    float2* h2 = (float2*)h;
    const float2* o2 = (const float2*)t2;
    float2 hv = h2[(size_t)row * 64 + lane];
    float2 ov = o2[(size_t)row * 64 + lane];
    float vx = hv.x + ov.x, vy = hv.y + ov.y;
    float s = vx + vy;
#pragma unroll
    for (int m = 32; m; m >>= 1) s += __shfl_xor(s, m);
    float mu = s * (1.0f / 128.0f);
    float dx = vx - mu, dy = vy - mu;
    float q = dx * dx + dy * dy;
#pragma unroll
    for (int m = 32; m; m >>= 1) q += __shfl_xor(q, m);
    float rstd = rsqrtf(q * (1.0f / 128.0f) + 1e-5f);
    float2 o;
    o.x = dx * rstd * g[lane * 2 + 0] + b[lane * 2 + 0];
    o.y = dy * rstd * g[lane * 2 + 1] + b[lane * 2 + 1];
    h2[(size_t)row * 64 + lane] = o;
}

// readout: one wave per atom; lane j holds hidden unit j of ro layer 1
__global__ __launch_bounds__(256) void k_ro(const float* __restrict__ h,
                                            const float* __restrict__ w1,
                                            const float* __restrict__ b1,
                                            const float* __restrict__ w2,
                                            const float* __restrict__ b2,
                                            float* __restrict__ out) {
    int atom = blockIdx.x * 4 + (threadIdx.x >> 6);
    int lane = threadIdx.x & 63;
    float acc = b1[lane];
    const float* hr = h + (size_t)atom * HIDD;
    for (int k = 0; k < HIDD; ++k) {
        float sh = silu_f(hr[k]);
        acc += sh * w1[k * 64 + lane];
    }
    float v = silu_f(acc) * w2[lane];
#pragma unroll
    for (int m = 32; m; m >>= 1) v += __shfl_xor(v, m);
    if (lane == 0) {
        atomicAdd(&out[atom >> 7], v + b2[0]);
    }
}

extern "C" void kernel_launch(void* const* d_in, const int* in_sizes, int n_in,
                              void* d_out, int out_size, void* d_ws, size_t ws_size,
                              hipStream_t stream) {
    const int*   Z   = (const int*)d_in[0];
    const float* pos = (const float*)d_in[1];
    const int*   ei  = (const int*)d_in[2];
    const float* ew  = (const float*)d_in[3];
    const float* ew1 = (const float*)d_in[4];
    const float* eb1 = (const float*)d_in[5];
    const float* ew2 = (const float*)d_in[6];
    const float* eb2 = (const float*)d_in[7];
    const float* liw = (const float*)d_in[8];
    const float* nw1 = (const float*)d_in[9];
    const float* nb1 = (const float*)d_in[10];
    const float* nw2 = (const float*)d_in[11];
    const float* nb2 = (const float*)d_in[12];
    const float* lng = (const float*)d_in[13];
    const float* lnb = (const float*)d_in[14];
    const float* rw1 = (const float*)d_in[15];
    const float* rb1 = (const float*)d_in[16];
    const float* rw2 = (const float*)d_in[17];
    const float* rb2 = (const float*)d_in[18];
    float* out = (float*)d_out;

    float* h    = (float*)d_ws;
    float* x    = h + (size_t)BN * HIDD;          // also reused as t2 (node MLP out)
    float* agg  = x + (size_t)BN * HIDD;
    float* t1   = agg + (size_t)BN * HIDD;
    float* lut  = t1 + (size_t)BN * HIDD;
    float* R    = lut + (size_t)TLUT * HIDD;
    float* tl   = R + (size_t)TLUT * NRBF;
    int*   bsrc = (int*)(tl + (size_t)TLUT * HIDD);
    float* bd   = (float*)(bsrc + (size_t)BN * CAP);
    int*   cnt  = (int*)(bd + (size_t)BN * CAP);

    hipMemsetAsync(cnt, 0, BN * sizeof(int), stream);
    hipMemsetAsync(out, 0, BB * sizeof(float), stream);

    k_embed<<<BN * HIDD / 256, 256, 0, stream>>>(Z, ew, h);
    k_edges<<<EE / 256, 256, 0, stream>>>(ei, pos, cnt, bsrc, bd);
    k_rbf<<<TLUT * NRBF / 256, 256, 0, stream>>>(R);

    for (int i = 0; i < NBLK; ++i) {
        // build filter LUT for this block: lut = silu(R@W1+b1)@W2+b2
        k_gemm<<<TLUT / 32, 256, 0, stream>>>(R, ew1 + (size_t)i * NRBF * HIDD,
                                              eb1 + i * HIDD, tl, NRBF, 1);
        k_gemm<<<TLUT / 32, 256, 0, stream>>>(tl, ew2 + (size_t)i * HIDD * HIDD,
                                              eb2 + i * HIDD, lut, HIDD, 0);
        // x = h @ lin_in_w[i]   (per-atom, not per-edge)
        k_gemm<<<BN / 32, 256, 0, stream>>>(h, liw + (size_t)i * HIDD * HIDD,
                                            nullptr, x, HIDD, 0);
        // agg[dst] = sum_e w(d_e) * x[src_e]
        k_agg<<<BN / 4, 256, 0, stream>>>(cnt, bsrc, bd, lut, x, agg);
        // node MLP
        k_gemm<<<BN / 32, 256, 0, stream>>>(agg, nw1 + (size_t)i * HIDD * HIDD,
                                            nb1 + i * HIDD, t1, HIDD, 1);
        k_gemm<<<BN / 32, 256, 0, stream>>>(t1, nw2 + (size_t)i * HIDD * HIDD,
                                            nb2 + i * HIDD, x, HIDD, 0);
        // h = LN(h + out)
        k_ln<<<BN / 4, 256, 0, stream>>>(h, x, lng + i * HIDD, lnb + i * HIDD);
    }

    k_ro<<<BN / 4, 256, 0, stream>>>(h, rw1, rb1, rw2, rb2, out);
}

// Round 2
// 404.318 us; speedup vs baseline: 1.3462x; 1.3462x over previous
//
#include <hip/hip_runtime.h>

#define BN 8192
#define EE 262144
#define HIDD 128
#define NRBF 64
#define NBLK 4
#define TLUT 1024
#define CAP 128
#define RCUTF 6.0f
#define GAMMAF (10.0f / 36.0f)

typedef unsigned short u16;

__device__ __forceinline__ float silu_f(float v) {
    return v / (1.0f + __expf(-v));
}
__device__ __forceinline__ float bf2f(u16 u) {
    return __uint_as_float(((unsigned)u) << 16);
}
__device__ __forceinline__ u16 f2bf(float f) {
    unsigned u = __float_as_uint(f);
    unsigned r = u + 0x7FFFu + ((u >> 16) & 1u);
    return (u16)(r >> 16);
}

// h[a][f] = embed_w[Z[a]][f]
__global__ void k_embed(const int* __restrict__ Z, const float* __restrict__ ew,
                        float* __restrict__ h) {
    int i = blockIdx.x * 256 + threadIdx.x;
    int a = i >> 7, f = i & 127;
    h[i] = ew[Z[a] * HIDD + f];
}

// bucket edges by dst; meta = (src, dist)
__global__ void k_edges(const int* __restrict__ ei, const float* __restrict__ pos,
                        int* __restrict__ cnt, int2* __restrict__ meta) {
    int e = blockIdx.x * 256 + threadIdx.x;
    int s = ei[e];
    int d = ei[EE + e];
    float dx = pos[s * 3 + 0] - pos[d * 3 + 0];
    float dy = pos[s * 3 + 1] - pos[d * 3 + 1];
    float dz = pos[s * 3 + 2] - pos[d * 3 + 2];
    float dist = fminf(sqrtf(dx * dx + dy * dy + dz * dz), RCUTF);
    int p = atomicAdd(&cnt[d], 1);
    if (p < CAP) meta[d * CAP + p] = make_int2(s, __float_as_int(dist));
}

// R[t][k] = exp(-gamma*(d_t - c_k)^2) on the LUT grid
__global__ void k_rbf(float* __restrict__ R) {
    int i = blockIdx.x * 256 + threadIdx.x;
    int t = i >> 6, k = i & 63;
    float d = t * (RCUTF / (TLUT - 1));
    float c = k * (RCUTF / 63.0f);
    float u = d - c;
    R[i] = __expf(-GAMMAF * u * u);
}

#define GEMM_INNER(ACC, AROW0, K)                                              \
    {                                                                          \
        float4 wv = *(float4*)&Ws[K][c0];                                      \
        float a0 = AROW0[0], a1 = AROW0[1], a2 = AROW0[2], a3 = AROW0[3];      \
        ACC[0][0] += a0 * wv.x; ACC[0][1] += a0 * wv.y;                        \
        ACC[0][2] += a0 * wv.z; ACC[0][3] += a0 * wv.w;                        \
        ACC[1][0] += a1 * wv.x; ACC[1][1] += a1 * wv.y;                        \
        ACC[1][2] += a1 * wv.z; ACC[1][3] += a1 * wv.w;                        \
        ACC[2][0] += a2 * wv.x; ACC[2][1] += a2 * wv.y;                        \
        ACC[2][2] += a2 * wv.z; ACC[2][3] += a2 * wv.w;                        \
        ACC[3][0] += a3 * wv.x; ACC[3][1] += a3 * wv.y;                        \
        ACC[3][2] += a3 * wv.z; ACC[3][3] += a3 * wv.w;                        \
    }

// fused edge-filter LUT: lut = (silu(R@W1+b1))@W2 + b2, bf16 out. grid=TLUT/32
__global__ __launch_bounds__(256) void k_lutfused(const float* __restrict__ R,
                                                  const float* __restrict__ W1,
                                                  const float* __restrict__ b1,
                                                  const float* __restrict__ W2,
                                                  const float* __restrict__ b2,
                                                  u16* __restrict__ lutb) {
    __shared__ float As[32][32];
    __shared__ float Ws[32][128];
    __shared__ float T[32][128];
    int tid = threadIdx.x;
    int tx = tid & 31, ty = tid >> 5;
    int c0 = tx * 4, rr = ty * 4;
    int r0 = blockIdx.x * 32;
    float acc[4][4] = {};
    for (int kc = 0; kc < NRBF; kc += 32) {
        int lr = tid >> 3, lc = (tid & 7) * 4;
        *(float4*)&As[lr][lc] = *(const float4*)&R[(size_t)(r0 + lr) * NRBF + kc + lc];
#pragma unroll
        for (int j = 0; j < 4; ++j) {
            int idx = tid + j * 256;
            int wr = idx >> 5, wc = (idx & 31) * 4;
            *(float4*)&Ws[wr][wc] = *(const float4*)&W1[(size_t)(kc + wr) * HIDD + wc];
        }
        __syncthreads();
#pragma unroll 8
        for (int k = 0; k < 32; ++k) {
            float ar[4] = {As[rr][k], As[rr + 1][k], As[rr + 2][k], As[rr + 3][k]};
            GEMM_INNER(acc, ar, k)
        }
        __syncthreads();
    }
#pragma unroll
    for (int i = 0; i < 4; ++i)
#pragma unroll
        for (int j = 0; j < 4; ++j)
            T[rr + i][c0 + j] = silu_f(acc[i][j] + b1[c0 + j]);
    float acc2[4][4] = {};
    __syncthreads();
    for (int kc = 0; kc < HIDD; kc += 32) {
#pragma unroll
        for (int j = 0; j < 4; ++j) {
            int idx = tid + j * 256;
            int wr = idx >> 5, wc = (idx & 31) * 4;
            *(float4*)&Ws[wr][wc] = *(const float4*)&W2[(size_t)(kc + wr) * HIDD + wc];
        }
        __syncthreads();
#pragma unroll 8
        for (int k = 0; k < 32; ++k) {
            float ar[4] = {T[rr][kc + k], T[rr + 1][kc + k], T[rr + 2][kc + k],
                           T[rr + 3][kc + k]};
            GEMM_INNER(acc2, ar, k)
        }
        __syncthreads();
    }
#pragma unroll
    for (int i = 0; i < 4; ++i) {
        ushort4 o;
        o.x = f2bf(acc2[i][0] + b2[c0 + 0]);
        o.y = f2bf(acc2[i][1] + b2[c0 + 1]);
        o.z = f2bf(acc2[i][2] + b2[c0 + 2]);
        o.w = f2bf(acc2[i][3] + b2[c0 + 3]);
        *(ushort4*)&lutb[(size_t)(r0 + rr + i) * HIDD + c0] = o;
    }
}

// x = h @ W (K=N=128), bf16 out. grid=BN/32
__global__ __launch_bounds__(256) void k_xgemm(const float* __restrict__ A,
                                               const float* __restrict__ W,
                                               u16* __restrict__ C) {
    __shared__ float As[32][32];
    __shared__ float Ws[32][128];
    int tid = threadIdx.x;
    int tx = tid & 31, ty = tid >> 5;
    int c0 = tx * 4, rr = ty * 4;
    int r0 = blockIdx.x * 32;
    float acc[4][4] = {};
    for (int kc = 0; kc < HIDD; kc += 32) {
        int lr = tid >> 3, lc = (tid & 7) * 4;
        *(float4*)&As[lr][lc] = *(const float4*)&A[(size_t)(r0 + lr) * HIDD + kc + lc];
#pragma unroll
        for (int j = 0; j < 4; ++j) {
            int idx = tid + j * 256;
            int wr = idx >> 5, wc = (idx & 31) * 4;
            *(float4*)&Ws[wr][wc] = *(const float4*)&W[(size_t)(kc + wr) * HIDD + wc];
        }
        __syncthreads();
#pragma unroll 8
        for (int k = 0; k < 32; ++k) {
            float ar[4] = {As[rr][k], As[rr + 1][k], As[rr + 2][k], As[rr + 3][k]};
            GEMM_INNER(acc, ar, k)
        }
        __syncthreads();
    }
#pragma unroll
    for (int i = 0; i < 4; ++i) {
        ushort4 o;
        o.x = f2bf(acc[i][0]);
        o.y = f2bf(acc[i][1]);
        o.z = f2bf(acc[i][2]);
        o.w = f2bf(acc[i][3]);
        *(ushort4*)&C[(size_t)(r0 + rr + i) * HIDD + c0] = o;
    }
}

// one wave per dst atom: agg[dst][:] = sum_e w(d_e) * x[src_e][:]  (bf16 in, f32 out)
__global__ __launch_bounds__(256) void k_agg(const int* __restrict__ cnt,
                                             const int2* __restrict__ meta,
                                             const u16* __restrict__ lutb,
                                             const u16* __restrict__ xb,
                                             float* __restrict__ agg) {
    int dst = blockIdx.x * 4 + (threadIdx.x >> 6);
    int lane = threadIdx.x & 63;
    int n = cnt[dst];
    n = n > CAP ? CAP : n;
    const ushort2* l2 = (const ushort2*)lutb;
    const ushort2* x2 = (const ushort2*)xb;
    float ax = 0.0f, ay = 0.0f;
    for (int t = 0; t < n; ++t) {
        int2 md = meta[dst * CAP + t];
        int s = md.x;
        float dd = __int_as_float(md.y);
        float f = dd * ((TLUT - 1) / RCUTF);
        int i0 = (int)f;
        i0 = i0 > TLUT - 2 ? TLUT - 2 : i0;
        float fr = f - (float)i0;
        ushort2 l0 = l2[i0 * 64 + lane];
        ushort2 l1 = l2[(i0 + 1) * 64 + lane];
        ushort2 xv = x2[(size_t)s * 64 + lane];
        float w0x = bf2f(l0.x), w0y = bf2f(l0.y);
        float wx = w0x + fr * (bf2f(l1.x) - w0x);
        float wy = w0y + fr * (bf2f(l1.y) - w0y);
        ax += wx * bf2f(xv.x);
        ay += wy * bf2f(xv.y);
    }
    float2 o;
    o.x = ax;
    o.y = ay;
    ((float2*)agg)[(size_t)dst * 64 + lane] = o;
}

// fused node MLP + residual + LN: h = LN(h + silu(agg@W1+b1)@W2+b2)*g+b. grid=BN/32
__global__ __launch_bounds__(256) void k_node(const float* __restrict__ agg,
                                              const float* __restrict__ W1,
                                              const float* __restrict__ b1,
                                              const float* __restrict__ W2,
                                              const float* __restrict__ b2,
                                              const float* __restrict__ g,
                                              const float* __restrict__ bb,
                                              float* __restrict__ h) {
    __shared__ float As[32][32];
    __shared__ float Ws[32][128];
    __shared__ float T[32][128];
    int tid = threadIdx.x;
    int tx = tid & 31, ty = tid >> 5;
    int c0 = tx * 4, rr = ty * 4;
    int r0 = blockIdx.x * 32;
    float acc[4][4] = {};
    for (int kc = 0; kc < HIDD; kc += 32) {
        int lr = tid >> 3, lc = (tid & 7) * 4;
        *(float4*)&As[lr][lc] = *(const float4*)&agg[(size_t)(r0 + lr) * HIDD + kc + lc];
#pragma unroll
        for (int j = 0; j < 4; ++j) {
            int idx = tid + j * 256;
            int wr = idx >> 5, wc = (idx & 31) * 4;
            *(float4*)&Ws[wr][wc] = *(const float4*)&W1[(size_t)(kc + wr) * HIDD + wc];
        }
        __syncthreads();
#pragma unroll 8
        for (int k = 0; k < 32; ++k) {
            float ar[4] = {As[rr][k], As[rr + 1][k], As[rr + 2][k], As[rr + 3][k]};
            GEMM_INNER(acc, ar, k)
        }
        __syncthreads();
    }
#pragma unroll
    for (int i = 0; i < 4; ++i)
#pragma unroll
        for (int j = 0; j < 4; ++j)
            T[rr + i][c0 + j] = silu_f(acc[i][j] + b1[c0 + j]);
    float acc2[4][4] = {};
    __syncthreads();
    for (int kc = 0; kc < HIDD; kc += 32) {
#pragma unroll
        for (int j = 0; j < 4; ++j) {
            int idx = tid + j * 256;
            int wr = idx >> 5, wc = (idx & 31) * 4;
            *(float4*)&Ws[wr][wc] = *(const float4*)&W2[(size_t)(kc + wr) * HIDD + wc];
        }
        __syncthreads();
#pragma unroll 8
        for (int k = 0; k < 32; ++k) {
            float ar[4] = {T[rr][kc + k], T[rr + 1][kc + k], T[rr + 2][kc + k],
                           T[rr + 3][kc + k]};
            GEMM_INNER(acc2, ar, k)
        }
        __syncthreads();
    }
    // epilogue: residual + LayerNorm
    float v[4][4];
#pragma unroll
    for (int i = 0; i < 4; ++i) {
        float4 hv = *(const float4*)&h[(size_t)(r0 + rr + i) * HIDD + c0];
        v[i][0] = acc2[i][0] + b2[c0 + 0] + hv.x;
        v[i][1] = acc2[i][1] + b2[c0 + 1] + hv.y;
        v[i][2] = acc2[i][2] + b2[c0 + 2] + hv.z;
        v[i][3] = acc2[i][3] + b2[c0 + 3] + hv.w;
    }
    float s[4], q[4];
#pragma unroll
    for (int i = 0; i < 4; ++i) s[i] = v[i][0] + v[i][1] + v[i][2] + v[i][3];
#pragma unroll
    for (int m = 1; m < 32; m <<= 1) {
#pragma unroll
        for (int i = 0; i < 4; ++i) s[i] += __shfl_xor(s[i], m);
    }
#pragma unroll
    for (int i = 0; i < 4; ++i) {
        float mu = s[i] * (1.0f / 128.0f);
        v[i][0] -= mu; v[i][1] -= mu; v[i][2] -= mu; v[i][3] -= mu;
        q[i] = v[i][0] * v[i][0] + v[i][1] * v[i][1] + v[i][2] * v[i][2] +
               v[i][3] * v[i][3];
    }
#pragma unroll
    for (int m = 1; m < 32; m <<= 1) {
#pragma unroll
        for (int i = 0; i < 4; ++i) q[i] += __shfl_xor(q[i], m);
    }
    float4 gv = *(const float4*)&g[c0];
    float4 bv = *(const float4*)&bb[c0];
#pragma unroll
    for (int i = 0; i < 4; ++i) {
        float rstd = rsqrtf(q[i] * (1.0f / 128.0f) + 1e-5f);
        float4 o;
        o.x = v[i][0] * rstd * gv.x + bv.x;
        o.y = v[i][1] * rstd * gv.y + bv.y;
        o.z = v[i][2] * rstd * gv.z + bv.z;
        o.w = v[i][3] * rstd * gv.w + bv.w;
        *(float4*)&h[(size_t)(r0 + rr + i) * HIDD + c0] = o;
    }
}

// fused readout: per-graph energy += sum_rows silu(silu(h)@w1+b1)@w2+b2. grid=BN/32
__global__ __launch_bounds__(256) void k_ro2(const float* __restrict__ h,
                                             const float* __restrict__ w1,
                                             const float* __restrict__ b1,
                                             const float* __restrict__ w2,
                                             const float* __restrict__ b2,
                                             float* __restrict__ out) {
    __shared__ float As[32][33];
    __shared__ float Ws[32][64];
    int tid = threadIdx.x;
    int tx = tid & 15, ty = tid >> 4;
    int c0 = tx * 4, rr = ty * 2;
    int r0 = blockIdx.x * 32;
    float acc[2][4] = {};
    for (int kc = 0; kc < HIDD; kc += 32) {
        int lr = tid >> 3, lc = (tid & 7) * 4;
        float4 av = *(const float4*)&h[(size_t)(r0 + lr) * HIDD + kc + lc];
        As[lr][lc + 0] = silu_f(av.x);
        As[lr][lc + 1] = silu_f(av.y);
        As[lr][lc + 2] = silu_f(av.z);
        As[lr][lc + 3] = silu_f(av.w);
#pragma unroll
        for (int j = 0; j < 2; ++j) {
            int idx = tid + j * 256;
            int wr = idx >> 4, wc = (idx & 15) * 4;
            *(float4*)&Ws[wr][wc] = *(const float4*)&w1[(size_t)(kc + wr) * 64 + wc];
        }
        __syncthreads();
#pragma unroll 8
        for (int k = 0; k < 32; ++k) {
            float4 wv = *(float4*)&Ws[k][c0];
            float a0 = As[rr][k], a1 = As[rr + 1][k];
            acc[0][0] += a0 * wv.x; acc[0][1] += a0 * wv.y;
            acc[0][2] += a0 * wv.z; acc[0][3] += a0 * wv.w;
            acc[1][0] += a1 * wv.x; acc[1][1] += a1 * wv.y;
            acc[1][2] += a1 * wv.z; acc[1][3] += a1 * wv.w;
        }
        __syncthreads();
    }
    float p0 = 0.0f, p1 = 0.0f;
#pragma unroll
    for (int j = 0; j < 4; ++j) {
        float wj = w2[c0 + j];
        p0 += silu_f(acc[0][j] + b1[c0 + j]) * wj;
        p1 += silu_f(acc[1][j] + b1[c0 + j]) * wj;
    }
#pragma unroll
    for (int m = 1; m < 16; m <<= 1) {
        p0 += __shfl_xor(p0, m);
        p1 += __shfl_xor(p1, m);
    }
    if (tx == 0) atomicAdd(&out[r0 >> 7], p0 + p1 + 2.0f * b2[0]);
}

extern "C" void kernel_launch(void* const* d_in, const int* in_sizes, int n_in,
                              void* d_out, int out_size, void* d_ws, size_t ws_size,
                              hipStream_t stream) {
    const int*   Z   = (const int*)d_in[0];
    const float* pos = (const float*)d_in[1];
    const int*   ei  = (const int*)d_in[2];
    const float* ew  = (const float*)d_in[3];
    const float* ew1 = (const float*)d_in[4];
    const float* eb1 = (const float*)d_in[5];
    const float* ew2 = (const float*)d_in[6];
    const float* eb2 = (const float*)d_in[7];
    const float* liw = (const float*)d_in[8];
    const float* nw1 = (const float*)d_in[9];
    const float* nb1 = (const float*)d_in[10];
    const float* nw2 = (const float*)d_in[11];
    const float* nb2 = (const float*)d_in[12];
    const float* lng = (const float*)d_in[13];
    const float* lnb = (const float*)d_in[14];
    const float* rw1 = (const float*)d_in[15];
    const float* rb1 = (const float*)d_in[16];
    const float* rw2 = (const float*)d_in[17];
    const float* rb2 = (const float*)d_in[18];
    float* out = (float*)d_out;

    float* h    = (float*)d_ws;
    float* agg  = h + (size_t)BN * HIDD;
    float* R    = agg + (size_t)BN * HIDD;
    u16*   lutb = (u16*)(R + (size_t)TLUT * NRBF);
    u16*   xb   = lutb + (size_t)TLUT * HIDD;
    int*   cnt  = (int*)(xb + (size_t)BN * HIDD);
    int2*  meta = (int2*)(cnt + BN);

    hipMemsetAsync(cnt, 0, BN * sizeof(int), stream);
    hipMemsetAsync(out, 0, out_size * sizeof(float), stream);

    k_embed<<<BN * HIDD / 256, 256, 0, stream>>>(Z, ew, h);
    k_edges<<<EE / 256, 256, 0, stream>>>(ei, pos, cnt, meta);
    k_rbf<<<TLUT * NRBF / 256, 256, 0, stream>>>(R);

    for (int i = 0; i < NBLK; ++i) {
        k_lutfused<<<TLUT / 32, 256, 0, stream>>>(
            R, ew1 + (size_t)i * NRBF * HIDD, eb1 + i * HIDD,
            ew2 + (size_t)i * HIDD * HIDD, eb2 + i * HIDD, lutb);
        k_xgemm<<<BN / 32, 256, 0, stream>>>(h, liw + (size_t)i * HIDD * HIDD, xb);
        k_agg<<<BN / 4, 256, 0, stream>>>(cnt, meta, lutb, xb, agg);
        k_node<<<BN / 32, 256, 0, stream>>>(
            agg, nw1 + (size_t)i * HIDD * HIDD, nb1 + i * HIDD,
            nw2 + (size_t)i * HIDD * HIDD, nb2 + i * HIDD,
            lng + i * HIDD, lnb + i * HIDD, h);
    }

    k_ro2<<<BN / 32, 256, 0, stream>>>(h, rw1, rb1, rw2, rb2, out);
}

// Round 3
// 394.179 us; speedup vs baseline: 1.3808x; 1.0257x over previous
//
#include <hip/hip_runtime.h>

#define BN 8192
#define EE 262144
#define HIDD 128
#define NRBF 64
#define NBLK 4
#define TLUT 1024
#define CAP 128
#define ROWS 16
#define RCUTF 6.0f
#define GAMMAF (10.0f / 36.0f)

typedef unsigned short u16;
typedef __attribute__((ext_vector_type(8))) short short8x;
typedef __attribute__((ext_vector_type(4))) float f32x4;

__device__ __forceinline__ float silu_f(float v) {
    return v / (1.0f + __expf(-v));
}
__device__ __forceinline__ float bf2f(u16 u) {
    return __uint_as_float(((unsigned)u) << 16);
}
__device__ __forceinline__ u16 f2bf(float f) {
    unsigned u = __float_as_uint(f);
    unsigned r = u + 0x7FFFu + ((u >> 16) & 1u);
    return (u16)(r >> 16);
}

// ---- prep: bf16-transpose weights to [n][k], zero cnt & out -----------------
__global__ void k_prep(const float* __restrict__ liw, const float* __restrict__ nw1,
                       const float* __restrict__ nw2, const float* __restrict__ ro1,
                       u16* __restrict__ liwT, u16* __restrict__ nw1T,
                       u16* __restrict__ nw2T, u16* __restrict__ ro1T,
                       int* __restrict__ cnt, float* __restrict__ out, int out_n) {
    int id0 = blockIdx.x * 256 + threadIdx.x;
    for (int id = id0; id < 12 * 16384; id += 65536) {
        int which = id >> 14;          // 0..11
        int r = id & 16383;
        int n = r >> 7, k = r & 127;
        const float* src = which < 4 ? liw : (which < 8 ? nw1 : nw2);
        u16* dst = which < 4 ? liwT : (which < 8 ? nw1T : nw2T);
        int b = which & 3;
        dst[b * 16384 + n * 128 + k] = f2bf(src[(size_t)b * 16384 + k * 128 + n]);
    }
    if (id0 < 8192) {
        cnt[id0] = 0;
        int n = id0 >> 7, k = id0 & 127;          // n<64
        ro1T[n * 128 + k] = f2bf(ro1[k * 64 + n]);
        if (id0 < out_n) out[id0] = 0.0f;
    }
}

// ---- edges: bucket by dst, pack (src, i0|fr) --------------------------------
__global__ void k_edges(const int* __restrict__ ei, const float* __restrict__ pos,
                        int* __restrict__ cnt, int2* __restrict__ meta) {
    int e = blockIdx.x * 256 + threadIdx.x;
    int s = ei[e];
    int d = ei[EE + e];
    float dx = pos[s * 3 + 0] - pos[d * 3 + 0];
    float dy = pos[s * 3 + 1] - pos[d * 3 + 1];
    float dz = pos[s * 3 + 2] - pos[d * 3 + 2];
    float dist = fminf(sqrtf(dx * dx + dy * dy + dz * dz), RCUTF);
    float f = dist * ((TLUT - 1) / RCUTF);
    int i0 = (int)f;
    i0 = i0 > TLUT - 2 ? TLUT - 2 : i0;
    float fr = f - (float)i0;
    int y = (i0 << 16) | (int)(fr * 65535.0f);
    int p = atomicAdd(&cnt[d], 1);
    if (p < CAP) meta[d * CAP + p] = make_int2(s, y);
}

// ---- filter LUT for all 4 blocks (RBF inline, VALU GEMM) --------------------
#define GEMM_INNER(ACC, AROW0, K)                                              \
    {                                                                          \
        float4 wv = *(float4*)&Ws[K][c0];                                      \
        float a0 = AROW0[0], a1 = AROW0[1], a2 = AROW0[2], a3 = AROW0[3];      \
        ACC[0][0] += a0 * wv.x; ACC[0][1] += a0 * wv.y;                        \
        ACC[0][2] += a0 * wv.z; ACC[0][3] += a0 * wv.w;                        \
        ACC[1][0] += a1 * wv.x; ACC[1][1] += a1 * wv.y;                        \
        ACC[1][2] += a1 * wv.z; ACC[1][3] += a1 * wv.w;                        \
        ACC[2][0] += a2 * wv.x; ACC[2][1] += a2 * wv.y;                        \
        ACC[2][2] += a2 * wv.z; ACC[2][3] += a2 * wv.w;                        \
        ACC[3][0] += a3 * wv.x; ACC[3][1] += a3 * wv.y;                        \
        ACC[3][2] += a3 * wv.z; ACC[3][3] += a3 * wv.w;                        \
    }

__global__ __launch_bounds__(256) void k_lutall(const float* __restrict__ W1a,
                                                const float* __restrict__ b1a,
                                                const float* __restrict__ W2a,
                                                const float* __restrict__ b2a,
                                                u16* __restrict__ lutall) {
    __shared__ float As[32][33];
    __shared__ float Ws[32][128];
    __shared__ float T[32][128];
    int blk = blockIdx.x >> 5;
    int r0 = (blockIdx.x & 31) * 32;
    const float* W1 = W1a + (size_t)blk * NRBF * HIDD;
    const float* b1 = b1a + blk * HIDD;
    const float* W2 = W2a + (size_t)blk * HIDD * HIDD;
    const float* b2 = b2a + blk * HIDD;
    u16* lutb = lutall + (size_t)blk * TLUT * HIDD;
    int tid = threadIdx.x;
    int tx = tid & 31, ty = tid >> 5;
    int c0 = tx * 4, rr = ty * 4;
    float acc[4][4] = {};
    for (int kc = 0; kc < NRBF; kc += 32) {
        int lr = tid >> 3, lc = (tid & 7) * 4;
        float dt = (r0 + lr) * (RCUTF / (TLUT - 1));
#pragma unroll
        for (int j = 0; j < 4; ++j) {
            float c = (kc + lc + j) * (RCUTF / 63.0f);
            float u = dt - c;
            As[lr][lc + j] = __expf(-GAMMAF * u * u);
        }
#pragma unroll
        for (int j = 0; j < 4; ++j) {
            int idx = tid + j * 256;
            int wr = idx >> 5, wc = (idx & 31) * 4;
            *(float4*)&Ws[wr][wc] = *(const float4*)&W1[(size_t)(kc + wr) * HIDD + wc];
        }
        __syncthreads();
#pragma unroll 8
        for (int k = 0; k < 32; ++k) {
            float ar[4] = {As[rr][k], As[rr + 1][k], As[rr + 2][k], As[rr + 3][k]};
            GEMM_INNER(acc, ar, k)
        }
        __syncthreads();
    }
#pragma unroll
    for (int i = 0; i < 4; ++i)
#pragma unroll
        for (int j = 0; j < 4; ++j)
            T[rr + i][c0 + j] = silu_f(acc[i][j] + b1[c0 + j]);
    float acc2[4][4] = {};
    __syncthreads();
    for (int kc = 0; kc < HIDD; kc += 32) {
#pragma unroll
        for (int j = 0; j < 4; ++j) {
            int idx = tid + j * 256;
            int wr = idx >> 5, wc = (idx & 31) * 4;
            *(float4*)&Ws[wr][wc] = *(const float4*)&W2[(size_t)(kc + wr) * HIDD + wc];
        }
        __syncthreads();
#pragma unroll 8
        for (int k = 0; k < 32; ++k) {
            float ar[4] = {T[rr][kc + k], T[rr + 1][kc + k], T[rr + 2][kc + k],
                           T[rr + 3][kc + k]};
            GEMM_INNER(acc2, ar, k)
        }
        __syncthreads();
    }
#pragma unroll
    for (int i = 0; i < 4; ++i) {
        ushort4 o;
        o.x = f2bf(acc2[i][0] + b2[c0 + 0]);
        o.y = f2bf(acc2[i][1] + b2[c0 + 1]);
        o.z = f2bf(acc2[i][2] + b2[c0 + 2]);
        o.w = f2bf(acc2[i][3] + b2[c0 + 3]);
        *(ushort4*)&lutb[(size_t)(r0 + rr + i) * HIDD + c0] = o;
    }
}

// ---- shared MFMA helpers ----------------------------------------------------
__device__ __forceinline__ void stage_wt(u16 Wt[][136], const u16* __restrict__ src,
                                         int rows) {
    int tid = threadIdx.x;
    int chunks = rows * 16;
    for (int idx = tid; idx < chunks; idx += 256) {
        int r = idx >> 4, c = (idx & 15) * 8;
        *(float4*)&Wt[r][c] = *(const float4*)&src[r * 128 + c];
    }
}

__device__ __forceinline__ void gemm_pair(const u16 A[][136], const u16 B[][136],
                                          int n0, f32x4& acc0, f32x4& acc1) {
    int l = threadIdx.x & 63;
    int m = l & 15, q = (l >> 4) * 8;
#pragma unroll
    for (int kc = 0; kc < 128; kc += 32) {
        short8x a = *(const short8x*)&A[m][kc + q];
        short8x b0 = *(const short8x*)&B[n0 + m][kc + q];
        short8x b1 = *(const short8x*)&B[n0 + 16 + m][kc + q];
        acc0 = __builtin_amdgcn_mfma_f32_16x16x32_bf16(a, b0, acc0, 0, 0, 0);
        acc1 = __builtin_amdgcn_mfma_f32_16x16x32_bf16(a, b1, acc1, 0, 0, 0);
    }
}

__device__ __forceinline__ void gemm_one(const u16 A[][136], const u16 B[][136],
                                         int n0, f32x4& acc0) {
    int l = threadIdx.x & 63;
    int m = l & 15, q = (l >> 4) * 8;
#pragma unroll
    for (int kc = 0; kc < 128; kc += 32) {
        short8x a = *(const short8x*)&A[m][kc + q];
        short8x b0 = *(const short8x*)&B[n0 + m][kc + q];
        acc0 = __builtin_amdgcn_mfma_f32_16x16x32_bf16(a, b0, acc0, 0, 0, 0);
    }
}

// ---- embed + x0 = h @ liw[0] ------------------------------------------------
__global__ __launch_bounds__(256, 2) void k_embedx(const int* __restrict__ Z,
                                                   const float* __restrict__ ew,
                                                   const u16* __restrict__ liwT0,
                                                   float* __restrict__ h,
                                                   u16* __restrict__ xb) {
    __shared__ u16 Wt[128][136];
    __shared__ u16 Ab[ROWS][136];
    int tid = threadIdx.x;
    int r0 = blockIdx.x * ROWS;
    // gather embedding rows: 16 threads per row, 8 cols each
    {
        int row = tid >> 4, c8 = (tid & 15) * 8;
        int z = Z[r0 + row];
        const float* er = ew + (size_t)z * HIDD + c8;
        float4 v0 = *(const float4*)er;
        float4 v1 = *(const float4*)(er + 4);
        float* hr = h + (size_t)(r0 + row) * HIDD + c8;
        *(float4*)hr = v0;
        *(float4*)(hr + 4) = v1;
        ushort4 a0, a1;
        a0.x = f2bf(v0.x); a0.y = f2bf(v0.y); a0.z = f2bf(v0.z); a0.w = f2bf(v0.w);
        a1.x = f2bf(v1.x); a1.y = f2bf(v1.y); a1.z = f2bf(v1.z); a1.w = f2bf(v1.w);
        *(ushort4*)&Ab[row][c8] = a0;
        *(ushort4*)&Ab[row][c8 + 4] = a1;
    }
    stage_wt(Wt, liwT0, 128);
    __syncthreads();
    int w = tid >> 6, l = tid & 63;
    int m = l & 15, q = l >> 4;
    f32x4 acc0 = {0, 0, 0, 0}, acc1 = {0, 0, 0, 0};
    gemm_pair(Ab, Wt, w * 32, acc0, acc1);
    int c = w * 32 + m;
#pragma unroll
    for (int r = 0; r < 4; ++r) {
        int row = q * 4 + r;
        u16* xr = xb + (size_t)(r0 + row) * HIDD;
        xr[c] = f2bf(acc0[r]);
        xr[c + 16] = f2bf(acc1[r]);
    }
}

// ---- fused per-block iteration ---------------------------------------------
__global__ __launch_bounds__(256, 2) void k_iter(
    const int* __restrict__ cnt, const int2* __restrict__ meta,
    const u16* __restrict__ lutb, const u16* __restrict__ xin,
    float* __restrict__ h,
    const u16* __restrict__ w1t, const float* __restrict__ b1,
    const u16* __restrict__ w2t, const float* __restrict__ b2,
    const float* __restrict__ g, const float* __restrict__ bb,
    const u16* __restrict__ w3t,      // liwT[i+1] or ro1T
    u16* __restrict__ xout,           // next x (null if last)
    int last, const float* __restrict__ rb1, const float* __restrict__ rw2,
    const float* __restrict__ rb2, float* __restrict__ out) {
    __shared__ u16 Wt[128][136];
    __shared__ u16 Ab[ROWS][136];
    __shared__ u16 Tb[ROWS][136];
    __shared__ float Hf[ROWS][132];
    __shared__ float red[4];
    int tid = threadIdx.x;
    int w = tid >> 6, l = tid & 63;
    int m = l & 15, q = l >> 4;
    int r0 = blockIdx.x * ROWS;

    // Phase A: edge gather, agg in registers -> Ab (bf16)
#pragma unroll
    for (int dd = 0; dd < 4; ++dd) {
        int dst = r0 + w * 4 + dd;
        int n = cnt[dst];
        n = n > CAP ? CAP : n;
        const int2* mp = meta + (size_t)dst * CAP;
        float ax = 0.0f, ay = 0.0f;
        for (int t = 0; t < n; ++t) {
            int2 md = mp[t];
            int s = md.x;
            int i0 = md.y >> 16;
            float fr = (md.y & 0xffff) * (1.0f / 65535.0f);
            const u16* lr0 = lutb + (size_t)i0 * HIDD + 2 * l;
            ushort2 l0 = *(const ushort2*)lr0;
            ushort2 l1 = *(const ushort2*)(lr0 + HIDD);
            ushort2 xv = *(const ushort2*)(xin + (size_t)s * HIDD + 2 * l);
            float w0x = bf2f(l0.x), w0y = bf2f(l0.y);
            float wx = fmaf(fr, bf2f(l1.x) - w0x, w0x);
            float wy = fmaf(fr, bf2f(l1.y) - w0y, w0y);
            ax = fmaf(wx, bf2f(xv.x), ax);
            ay = fmaf(wy, bf2f(xv.y), ay);
        }
        ushort2 o;
        o.x = f2bf(ax);
        o.y = f2bf(ay);
        *(ushort2*)&Ab[w * 4 + dd][2 * l] = o;
    }
    __syncthreads();

    // GEMM1: T = silu(agg @ W1 + b1)
    stage_wt(Wt, w1t, 128);
    __syncthreads();
    {
        f32x4 acc0 = {0, 0, 0, 0}, acc1 = {0, 0, 0, 0};
        gemm_pair(Ab, Wt, w * 32, acc0, acc1);
        int c = w * 32 + m;
        float bv0 = b1[c], bv1 = b1[c + 16];
#pragma unroll
        for (int r = 0; r < 4; ++r) {
            int row = q * 4 + r;
            Tb[row][c] = f2bf(silu_f(acc0[r] + bv0));
            Tb[row][c + 16] = f2bf(silu_f(acc1[r] + bv1));
        }
    }
    __syncthreads();

    // GEMM2: Hf = T @ W2 + b2 + h (residual)
    stage_wt(Wt, w2t, 128);
    __syncthreads();
    {
        f32x4 acc0 = {0, 0, 0, 0}, acc1 = {0, 0, 0, 0};
        gemm_pair(Tb, Wt, w * 32, acc0, acc1);
        int c = w * 32 + m;
        float bv0 = b2[c], bv1 = b2[c + 16];
#pragma unroll
        for (int r = 0; r < 4; ++r) {
            int row = q * 4 + r;
            const float* hr = h + (size_t)(r0 + row) * HIDD;
            Hf[row][c] = acc0[r] + bv0 + hr[c];
            Hf[row][c + 16] = acc1[r] + bv1 + hr[c + 16];
        }
    }
    __syncthreads();

    // LN: h_new = LN(Hf)*g + b ; Ab = bf16(h_new) (or bf16(silu(h_new)) if last)
    {
        float gx = g[2 * l], gy = g[2 * l + 1];
        float bx = bb[2 * l], by = bb[2 * l + 1];
#pragma unroll
        for (int rr = 0; rr < 4; ++rr) {
            int row = w * 4 + rr;
            float2 v = *(float2*)&Hf[row][2 * l];
            float s = v.x + v.y;
#pragma unroll
            for (int mm = 32; mm; mm >>= 1) s += __shfl_xor(s, mm);
            float mu = s * (1.0f / 128.0f);
            float dx = v.x - mu, dy = v.y - mu;
            float qq = dx * dx + dy * dy;
#pragma unroll
            for (int mm = 32; mm; mm >>= 1) qq += __shfl_xor(qq, mm);
            float rstd = rsqrtf(qq * (1.0f / 128.0f) + 1e-5f);
            float ox = dx * rstd * gx + bx;
            float oy = dy * rstd * gy + by;
            if (!last) {
                float2 o;
                o.x = ox;
                o.y = oy;
                *(float2*)&h[(size_t)(r0 + row) * HIDD + 2 * l] = o;
            }
            ushort2 a;
            a.x = f2bf(last ? silu_f(ox) : ox);
            a.y = f2bf(last ? silu_f(oy) : oy);
            *(ushort2*)&Ab[row][2 * l] = a;
        }
    }
    __syncthreads();

    // GEMM3: next x = h @ liw_next   OR   readout
    stage_wt(Wt, w3t, last ? 64 : 128);
    __syncthreads();
    if (!last) {
        f32x4 acc0 = {0, 0, 0, 0}, acc1 = {0, 0, 0, 0};
        gemm_pair(Ab, Wt, w * 32, acc0, acc1);
        int c = w * 32 + m;
#pragma unroll
        for (int r = 0; r < 4; ++r) {
            int row = q * 4 + r;
            u16* xr = xout + (size_t)(r0 + row) * HIDD;
            xr[c] = f2bf(acc0[r]);
            xr[c + 16] = f2bf(acc1[r]);
        }
    } else {
        f32x4 acc0 = {0, 0, 0, 0};
        gemm_one(Ab, Wt, w * 16, acc0);
        int c = w * 16 + m;
        float bv = rb1[c], wv = rw2[c];
        float tsum = 0.0f;
#pragma unroll
        for (int r = 0; r < 4; ++r) tsum += silu_f(acc0[r] + bv) * wv;
#pragma unroll
        for (int mm = 32; mm; mm >>= 1) tsum += __shfl_xor(tsum, mm);
        if (l == 0) red[w] = tsum;
        __syncthreads();
        if (tid == 0) {
            float tot = red[0] + red[1] + red[2] + red[3] + (float)ROWS * rb2[0];
            atomicAdd(&out[r0 >> 7], tot);
        }
    }
}

extern "C" void kernel_launch(void* const* d_in, const int* in_sizes, int n_in,
                              void* d_out, int out_size, void* d_ws, size_t ws_size,
                              hipStream_t stream) {
    const int*   Z   = (const int*)d_in[0];
    const float* pos = (const float*)d_in[1];
    const int*   ei  = (const int*)d_in[2];
    const float* ew  = (const float*)d_in[3];
    const float* ew1 = (const float*)d_in[4];
    const float* eb1 = (const float*)d_in[5];
    const float* ew2 = (const float*)d_in[6];
    const float* eb2 = (const float*)d_in[7];
    const float* liw = (const float*)d_in[8];
    const float* nw1 = (const float*)d_in[9];
    const float* nb1 = (const float*)d_in[10];
    const float* nw2 = (const float*)d_in[11];
    const float* nb2 = (const float*)d_in[12];
    const float* lng = (const float*)d_in[13];
    const float* lnb = (const float*)d_in[14];
    const float* rw1 = (const float*)d_in[15];
    const float* rb1 = (const float*)d_in[16];
    const float* rw2 = (const float*)d_in[17];
    const float* rb2 = (const float*)d_in[18];
    float* out = (float*)d_out;

    float* h    = (float*)d_ws;                         // 4 MB
    u16*   xb0  = (u16*)(h + (size_t)BN * HIDD);        // 2 MB
    u16*   xb1  = xb0 + (size_t)BN * HIDD;              // 2 MB
    u16*   lutall = xb1 + (size_t)BN * HIDD;            // 1 MB
    u16*   liwT = lutall + (size_t)NBLK * TLUT * HIDD;  // 128 KB
    u16*   nw1T = liwT + (size_t)NBLK * HIDD * HIDD;
    u16*   nw2T = nw1T + (size_t)NBLK * HIDD * HIDD;
    u16*   ro1T = nw2T + (size_t)NBLK * HIDD * HIDD;    // 16 KB
    int*   cnt  = (int*)(ro1T + 64 * HIDD);             // 32 KB
    int2*  meta = (int2*)(cnt + BN);                    // 8 MB

    k_prep<<<256, 256, 0, stream>>>(liw, nw1, nw2, rw1, liwT, nw1T, nw2T, ro1T,
                                    cnt, out, out_size);
    k_edges<<<EE / 256, 256, 0, stream>>>(ei, pos, cnt, meta);
    k_lutall<<<NBLK * (TLUT / 32), 256, 0, stream>>>(ew1, eb1, ew2, eb2, lutall);
    k_embedx<<<BN / ROWS, 256, 0, stream>>>(Z, ew, liwT, h, xb0);

    u16* xbuf[2] = {xb0, xb1};
    for (int i = 0; i < NBLK; ++i) {
        int last = (i == NBLK - 1);
        k_iter<<<BN / ROWS, 256, 0, stream>>>(
            cnt, meta, lutall + (size_t)i * TLUT * HIDD, xbuf[i & 1], h,
            nw1T + (size_t)i * HIDD * HIDD, nb1 + i * HIDD,
            nw2T + (size_t)i * HIDD * HIDD, nb2 + i * HIDD,
            lng + i * HIDD, lnb + i * HIDD,
            last ? ro1T : liwT + (size_t)(i + 1) * HIDD * HIDD,
            last ? (u16*)nullptr : xbuf[(i + 1) & 1],
            last, rb1, rw2, rb2, out);
    }
}

// Round 4
// 255.906 us; speedup vs baseline: 2.1269x; 1.5403x over previous
//
#include <hip/hip_runtime.h>

#define BN 8192
#define EE 262144
#define HIDD 128
#define NRBF 64
#define NBLK 4
#define TLUT 1024
#define CAP 128
#define MROWS 32
#define RCUTF 6.0f
#define GAMMAF (10.0f / 36.0f)

typedef unsigned short u16;
typedef __attribute__((ext_vector_type(8))) short short8x;
typedef __attribute__((ext_vector_type(4))) float f32x4;

__device__ __forceinline__ float silu_f(float v) {
    return v / (1.0f + __expf(-v));
}
__device__ __forceinline__ float bf2f(u16 u) {
    return __uint_as_float(((unsigned)u) << 16);
}
__device__ __forceinline__ u16 f2bf(float f) {
    unsigned u = __float_as_uint(f);
    unsigned r = u + 0x7FFFu + ((u >> 16) & 1u);
    return (u16)(r >> 16);
}

// ---- prep: bf16-transpose weights to [n][k], zero cnt & out -----------------
__global__ void k_prep(const float* __restrict__ liw, const float* __restrict__ nw1,
                       const float* __restrict__ nw2, const float* __restrict__ ro1,
                       u16* __restrict__ liwT, u16* __restrict__ nw1T,
                       u16* __restrict__ nw2T, u16* __restrict__ ro1T,
                       int* __restrict__ cnt, float* __restrict__ out, int out_n) {
    int id0 = blockIdx.x * 256 + threadIdx.x;
    for (int id = id0; id < 12 * 16384; id += 65536) {
        int which = id >> 14;          // 0..11
        int r = id & 16383;
        int n = r >> 7, k = r & 127;
        const float* src = which < 4 ? liw : (which < 8 ? nw1 : nw2);
        u16* dst = which < 4 ? liwT : (which < 8 ? nw1T : nw2T);
        int b = which & 3;
        dst[b * 16384 + n * 128 + k] = f2bf(src[(size_t)b * 16384 + k * 128 + n]);
    }
    if (id0 < 8192) {
        cnt[id0] = 0;
        int n = id0 >> 7, k = id0 & 127;          // n<64
        ro1T[n * 128 + k] = f2bf(ro1[k * 64 + n]);
        if (id0 < out_n) out[id0] = 0.0f;
    }
}

// ---- edges: bucket by dst, pack (src, i0|fr) --------------------------------
__global__ void k_edges(const int* __restrict__ ei, const float* __restrict__ pos,
                        int* __restrict__ cnt, int2* __restrict__ meta) {
    int e = blockIdx.x * 256 + threadIdx.x;
    int s = ei[e];
    int d = ei[EE + e];
    float dx = pos[s * 3 + 0] - pos[d * 3 + 0];
    float dy = pos[s * 3 + 1] - pos[d * 3 + 1];
    float dz = pos[s * 3 + 2] - pos[d * 3 + 2];
    float dist = fminf(sqrtf(dx * dx + dy * dy + dz * dz), RCUTF);
    float f = dist * ((TLUT - 1) / RCUTF);
    int i0 = (int)f;
    i0 = i0 > TLUT - 2 ? TLUT - 2 : i0;
    float fr = f - (float)i0;
    int y = (i0 << 16) | (int)(fr * 65535.0f);
    int p = atomicAdd(&cnt[d], 1);
    if (p < CAP) meta[d * CAP + p] = make_int2(s, y);
}

// ---- filter LUT for all 4 blocks (RBF inline, VALU GEMM), interleaved out ---
#define GEMM_INNER(ACC, AROW0, K)                                              \
    {                                                                          \
        float4 wv = *(float4*)&Ws[K][c0];                                      \
        float a0 = AROW0[0], a1 = AROW0[1], a2 = AROW0[2], a3 = AROW0[3];      \
        ACC[0][0] += a0 * wv.x; ACC[0][1] += a0 * wv.y;                        \
        ACC[0][2] += a0 * wv.z; ACC[0][3] += a0 * wv.w;                        \
        ACC[1][0] += a1 * wv.x; ACC[1][1] += a1 * wv.y;                        \
        ACC[1][2] += a1 * wv.z; ACC[1][3] += a1 * wv.w;                        \
        ACC[2][0] += a2 * wv.x; ACC[2][1] += a2 * wv.y;                        \
        ACC[2][2] += a2 * wv.z; ACC[2][3] += a2 * wv.w;                        \
        ACC[3][0] += a3 * wv.x; ACC[3][1] += a3 * wv.y;                        \
        ACC[3][2] += a3 * wv.z; ACC[3][3] += a3 * wv.w;                        \
    }

// lutp layout: [t][pair(64)][4] = {l0.lo, l0.hi, l1.lo, l1.hi} (l1 = row t+1)
__global__ __launch_bounds__(256) void k_lutall(const float* __restrict__ W1a,
                                                const float* __restrict__ b1a,
                                                const float* __restrict__ W2a,
                                                const float* __restrict__ b2a,
                                                u16* __restrict__ lutall) {
    __shared__ float As[32][33];
    __shared__ float Ws[32][128];
    __shared__ float T[32][128];
    int blk = blockIdx.x >> 5;
    int r0 = (blockIdx.x & 31) * 32;
    const float* W1 = W1a + (size_t)blk * NRBF * HIDD;
    const float* b1 = b1a + blk * HIDD;
    const float* W2 = W2a + (size_t)blk * HIDD * HIDD;
    const float* b2 = b2a + blk * HIDD;
    u16* lutp = lutall + (size_t)blk * TLUT * 256;
    int tid = threadIdx.x;
    int tx = tid & 31, ty = tid >> 5;
    int c0 = tx * 4, rr = ty * 4;
    float acc[4][4] = {};
    for (int kc = 0; kc < NRBF; kc += 32) {
        int lr = tid >> 3, lc = (tid & 7) * 4;
        float dt = (r0 + lr) * (RCUTF / (TLUT - 1));
#pragma unroll
        for (int j = 0; j < 4; ++j) {
            float c = (kc + lc + j) * (RCUTF / 63.0f);
            float u = dt - c;
            As[lr][lc + j] = __expf(-GAMMAF * u * u);
        }
#pragma unroll
        for (int j = 0; j < 4; ++j) {
            int idx = tid + j * 256;
            int wr = idx >> 5, wc = (idx & 31) * 4;
            *(float4*)&Ws[wr][wc] = *(const float4*)&W1[(size_t)(kc + wr) * HIDD + wc];
        }
        __syncthreads();
#pragma unroll 8
        for (int k = 0; k < 32; ++k) {
            float ar[4] = {As[rr][k], As[rr + 1][k], As[rr + 2][k], As[rr + 3][k]};
            GEMM_INNER(acc, ar, k)
        }
        __syncthreads();
    }
#pragma unroll
    for (int i = 0; i < 4; ++i)
#pragma unroll
        for (int j = 0; j < 4; ++j)
            T[rr + i][c0 + j] = silu_f(acc[i][j] + b1[c0 + j]);
    float acc2[4][4] = {};
    __syncthreads();
    for (int kc = 0; kc < HIDD; kc += 32) {
#pragma unroll
        for (int j = 0; j < 4; ++j) {
            int idx = tid + j * 256;
            int wr = idx >> 5, wc = (idx & 31) * 4;
            *(float4*)&Ws[wr][wc] = *(const float4*)&W2[(size_t)(kc + wr) * HIDD + wc];
        }
        __syncthreads();
#pragma unroll 8
        for (int k = 0; k < 32; ++k) {
            float ar[4] = {T[rr][kc + k], T[rr + 1][kc + k], T[rr + 2][kc + k],
                           T[rr + 3][kc + k]};
            GEMM_INNER(acc2, ar, k)
        }
        __syncthreads();
    }
#pragma unroll
    for (int i = 0; i < 4; ++i) {
        int t = r0 + rr + i;
        ushort2 a01, a23;
        a01.x = f2bf(acc2[i][0] + b2[c0 + 0]);
        a01.y = f2bf(acc2[i][1] + b2[c0 + 1]);
        a23.x = f2bf(acc2[i][2] + b2[c0 + 2]);
        a23.y = f2bf(acc2[i][3] + b2[c0 + 3]);
        u16* pa = lutp + ((size_t)t * 64 + (c0 >> 1)) * 4;
        *(ushort2*)(pa + 0) = a01;
        *(ushort2*)(pa + 4) = a23;
        if (t > 0) {
            u16* pb = lutp + ((size_t)(t - 1) * 64 + (c0 >> 1)) * 4;
            *(ushort2*)(pb + 2) = a01;
            *(ushort2*)(pb + 6) = a23;
        }
    }
}

// ---- gather: one wave per dst, meta preloaded into regs + shfl broadcast ----
__global__ __launch_bounds__(256, 4) void k_agg(const int* __restrict__ cnt,
                                                const int2* __restrict__ meta,
                                                const u16* __restrict__ lutp,
                                                const u16* __restrict__ xin,
                                                u16* __restrict__ aggb) {
    int dst = blockIdx.x * 4 + (threadIdx.x >> 6);
    int lane = threadIdx.x & 63;
    int n = cnt[dst];
    n = n > CAP ? CAP : n;
    const int2* mp = meta + (size_t)dst * CAP;
    int nm1 = n > 0 ? n - 1 : 0;
    int ja = lane < nm1 ? lane : nm1;
    int jb = 64 + lane < nm1 ? 64 + lane : nm1;
    int2 md1 = mp[ja];
    int2 md2 = mp[jb];
    float ax = 0.0f, ay = 0.0f;
#pragma unroll 4
    for (int t = 0; t < n; ++t) {
        int mx = __shfl(t < 64 ? md1.x : md2.x, t & 63);
        int my = __shfl(t < 64 ? md1.y : md2.y, t & 63);
        int i0 = my >> 16;
        float fr = (my & 0xffff) * (1.0f / 65535.0f);
        ushort4 lv = *(const ushort4*)&lutp[(((size_t)i0 << 6) + lane) << 2];
        ushort2 xv = *(const ushort2*)&xin[((size_t)mx << 7) + 2 * lane];
        float w0x = bf2f(lv.x), w0y = bf2f(lv.y);
        float wx = fmaf(fr, bf2f(lv.z) - w0x, w0x);
        float wy = fmaf(fr, bf2f(lv.w) - w0y, w0y);
        ax = fmaf(wx, bf2f(xv.x), ax);
        ay = fmaf(wy, bf2f(xv.y), ay);
    }
    ushort2 o;
    o.x = f2bf(ax);
    o.y = f2bf(ay);
    *(ushort2*)&aggb[((size_t)dst << 7) + 2 * lane] = o;
}

// ---- shared MFMA helpers ----------------------------------------------------
__device__ __forceinline__ void stage_wt(u16 Wt[][136], const u16* __restrict__ src,
                                         int rows) {
    int tid = threadIdx.x;
    int chunks = rows * 16;
    for (int idx = tid; idx < chunks; idx += 256) {
        int r = idx >> 4, c = (idx & 15) * 8;
        *(float4*)&Wt[r][c] = *(const float4*)&src[r * 128 + c];
    }
}

// 32-row x 32-col tile per wave: A rows {0..15,16..31}, B rows n0..n0+31
__device__ __forceinline__ void gemm32(const u16 A[][136], const u16 B[][136],
                                       int n0, f32x4 acc[2][2]) {
    int l = threadIdx.x & 63;
    int m = l & 15, q = (l >> 4) * 8;
#pragma unroll
    for (int kc = 0; kc < 128; kc += 32) {
        short8x a0 = *(const short8x*)&A[m][kc + q];
        short8x a1 = *(const short8x*)&A[16 + m][kc + q];
        short8x b0 = *(const short8x*)&B[n0 + m][kc + q];
        short8x b1 = *(const short8x*)&B[n0 + 16 + m][kc + q];
        acc[0][0] = __builtin_amdgcn_mfma_f32_16x16x32_bf16(a0, b0, acc[0][0], 0, 0, 0);
        acc[0][1] = __builtin_amdgcn_mfma_f32_16x16x32_bf16(a0, b1, acc[0][1], 0, 0, 0);
        acc[1][0] = __builtin_amdgcn_mfma_f32_16x16x32_bf16(a1, b0, acc[1][0], 0, 0, 0);
        acc[1][1] = __builtin_amdgcn_mfma_f32_16x16x32_bf16(a1, b1, acc[1][1], 0, 0, 0);
    }
}

// ---- embed + x0 = h @ liw[0] ------------------------------------------------
__global__ __launch_bounds__(256, 2) void k_embedx(const int* __restrict__ Z,
                                                   const float* __restrict__ ew,
                                                   const u16* __restrict__ liwT0,
                                                   float* __restrict__ h,
                                                   u16* __restrict__ xb) {
    __shared__ u16 Wt[128][136];
    __shared__ u16 Ab[MROWS][136];
    int tid = threadIdx.x;
    int r0 = blockIdx.x * MROWS;
    {
        int row = tid >> 3, c16 = (tid & 7) * 16;
        int z = Z[r0 + row];
        const float* er = ew + (size_t)z * HIDD + c16;
        float* hr = h + (size_t)(r0 + row) * HIDD + c16;
#pragma unroll
        for (int j = 0; j < 4; ++j) {
            float4 v = *(const float4*)(er + 4 * j);
            *(float4*)(hr + 4 * j) = v;
            ushort4 a;
            a.x = f2bf(v.x); a.y = f2bf(v.y); a.z = f2bf(v.z); a.w = f2bf(v.w);
            *(ushort4*)&Ab[row][c16 + 4 * j] = a;
        }
    }
    stage_wt(Wt, liwT0, 128);
    __syncthreads();
    int w = tid >> 6, l = tid & 63;
    int m = l & 15, q = l >> 4;
    f32x4 acc[2][2] = {{{0, 0, 0, 0}, {0, 0, 0, 0}}, {{0, 0, 0, 0}, {0, 0, 0, 0}}};
    gemm32(Ab, Wt, w * 32, acc);
    int c = w * 32 + m;
#pragma unroll
    for (int half = 0; half < 2; ++half)
#pragma unroll
        for (int r = 0; r < 4; ++r) {
            int row = half * 16 + q * 4 + r;
            u16* xr = xb + (size_t)(r0 + row) * HIDD;
            xr[c] = f2bf(acc[half][0][r]);
            xr[c + 16] = f2bf(acc[half][1][r]);
        }
}

// ---- fused node MLP + LN + (next-x | readout), MFMA ------------------------
__global__ __launch_bounds__(256, 2) void k_mlp(
    const u16* __restrict__ aggb, float* __restrict__ h,
    const u16* __restrict__ w1t, const float* __restrict__ b1,
    const u16* __restrict__ w2t, const float* __restrict__ b2,
    const float* __restrict__ g, const float* __restrict__ bb,
    const u16* __restrict__ w3t, u16* __restrict__ xout, int last,
    const float* __restrict__ rb1, const float* __restrict__ rw2,
    const float* __restrict__ rb2, float* __restrict__ out) {
    __shared__ u16 Wt[128][136];
    __shared__ u16 Ab[MROWS][136];
    __shared__ u16 Tb[MROWS][136];
    __shared__ float Hf[MROWS][132];
    __shared__ float red[4];
    int tid = threadIdx.x;
    int w = tid >> 6, l = tid & 63;
    int m = l & 15, q = l >> 4;
    int r0 = blockIdx.x * MROWS;

    {
        int row = tid >> 3, c8 = (tid & 7) * 16;
        const u16* ar = aggb + ((size_t)(r0 + row) << 7) + c8;
        *(float4*)&Ab[row][c8] = *(const float4*)ar;
        *(float4*)&Ab[row][c8 + 8] = *(const float4*)(ar + 8);
    }
    stage_wt(Wt, w1t, 128);
    __syncthreads();

    // GEMM1: T = silu(agg @ W1 + b1)
    {
        f32x4 acc[2][2] = {{{0, 0, 0, 0}, {0, 0, 0, 0}}, {{0, 0, 0, 0}, {0, 0, 0, 0}}};
        gemm32(Ab, Wt, w * 32, acc);
        int c = w * 32 + m;
        float bv0 = b1[c], bv1 = b1[c + 16];
        __syncthreads();   // done reading Wt (all waves) before restage
#pragma unroll
        for (int half = 0; half < 2; ++half)
#pragma unroll
            for (int r = 0; r < 4; ++r) {
                int row = half * 16 + q * 4 + r;
                Tb[row][c] = f2bf(silu_f(acc[half][0][r] + bv0));
                Tb[row][c + 16] = f2bf(silu_f(acc[half][1][r] + bv1));
            }
    }
    stage_wt(Wt, w2t, 128);
    __syncthreads();

    // GEMM2: Hf = T @ W2 + b2 + h
    {
        f32x4 acc[2][2] = {{{0, 0, 0, 0}, {0, 0, 0, 0}}, {{0, 0, 0, 0}, {0, 0, 0, 0}}};
        gemm32(Tb, Wt, w * 32, acc);
        int c = w * 32 + m;
        float bv0 = b2[c], bv1 = b2[c + 16];
        __syncthreads();
#pragma unroll
        for (int half = 0; half < 2; ++half)
#pragma unroll
            for (int r = 0; r < 4; ++r) {
                int row = half * 16 + q * 4 + r;
                const float* hr = h + (size_t)(r0 + row) * HIDD;
                Hf[row][c] = acc[half][0][r] + bv0 + hr[c];
                Hf[row][c + 16] = acc[half][1][r] + bv1 + hr[c + 16];
            }
    }
    stage_wt(Wt, w3t, last ? 64 : 128);
    __syncthreads();

    // LN: h_new = LN(Hf)*g + b ; Ab = bf16(h_new or silu(h_new))
    {
        float gx = g[2 * l], gy = g[2 * l + 1];
        float bx = bb[2 * l], by = bb[2 * l + 1];
#pragma unroll
        for (int rr = 0; rr < 8; ++rr) {
            int row = w * 8 + rr;
            float2 v = *(float2*)&Hf[row][2 * l];
            float s = v.x + v.y;
#pragma unroll
            for (int mm = 32; mm; mm >>= 1) s += __shfl_xor(s, mm);
            float mu = s * (1.0f / 128.0f);
            float dx = v.x - mu, dy = v.y - mu;
            float qq = dx * dx + dy * dy;
#pragma unroll
            for (int mm = 32; mm; mm >>= 1) qq += __shfl_xor(qq, mm);
            float rstd = rsqrtf(qq * (1.0f / 128.0f) + 1e-5f);
            float ox = dx * rstd * gx + bx;
            float oy = dy * rstd * gy + by;
            if (!last) {
                float2 o;
                o.x = ox;
                o.y = oy;
                *(float2*)&h[(size_t)(r0 + row) * HIDD + 2 * l] = o;
            }
            ushort2 a;
            a.x = f2bf(last ? silu_f(ox) : ox);
            a.y = f2bf(last ? silu_f(oy) : oy);
            *(ushort2*)&Ab[row][2 * l] = a;
        }
    }
    __syncthreads();

    if (!last) {
        f32x4 acc[2][2] = {{{0, 0, 0, 0}, {0, 0, 0, 0}}, {{0, 0, 0, 0}, {0, 0, 0, 0}}};
        gemm32(Ab, Wt, w * 32, acc);
        int c = w * 32 + m;
#pragma unroll
        for (int half = 0; half < 2; ++half)
#pragma unroll
            for (int r = 0; r < 4; ++r) {
                int row = half * 16 + q * 4 + r;
                u16* xr = xout + (size_t)(r0 + row) * HIDD;
                xr[c] = f2bf(acc[half][0][r]);
                xr[c + 16] = f2bf(acc[half][1][r]);
            }
    } else {
        f32x4 a0 = {0, 0, 0, 0}, a1 = {0, 0, 0, 0};
        int n0 = w * 16;
        int qq8 = q * 8;
#pragma unroll
        for (int kc = 0; kc < 128; kc += 32) {
            short8x av0 = *(const short8x*)&Ab[m][kc + qq8];
            short8x av1 = *(const short8x*)&Ab[16 + m][kc + qq8];
            short8x bv = *(const short8x*)&Wt[n0 + m][kc + qq8];
            a0 = __builtin_amdgcn_mfma_f32_16x16x32_bf16(av0, bv, a0, 0, 0, 0);
            a1 = __builtin_amdgcn_mfma_f32_16x16x32_bf16(av1, bv, a1, 0, 0, 0);
        }
        int c = n0 + m;
        float bv = rb1[c], wv = rw2[c];
        float tsum = 0.0f;
#pragma unroll
        for (int r = 0; r < 4; ++r) {
            tsum += silu_f(a0[r] + bv) * wv;
            tsum += silu_f(a1[r] + bv) * wv;
        }
#pragma unroll
        for (int mm = 32; mm; mm >>= 1) tsum += __shfl_xor(tsum, mm);
        if (l == 0) red[w] = tsum;
        __syncthreads();
        if (tid == 0) {
            float tot = red[0] + red[1] + red[2] + red[3] + (float)MROWS * rb2[0];
            atomicAdd(&out[r0 >> 7], tot);
        }
    }
}

extern "C" void kernel_launch(void* const* d_in, const int* in_sizes, int n_in,
                              void* d_out, int out_size, void* d_ws, size_t ws_size,
                              hipStream_t stream) {
    const int*   Z   = (const int*)d_in[0];
    const float* pos = (const float*)d_in[1];
    const int*   ei  = (const int*)d_in[2];
    const float* ew  = (const float*)d_in[3];
    const float* ew1 = (const float*)d_in[4];
    const float* eb1 = (const float*)d_in[5];
    const float* ew2 = (const float*)d_in[6];
    const float* eb2 = (const float*)d_in[7];
    const float* liw = (const float*)d_in[8];
    const float* nw1 = (const float*)d_in[9];
    const float* nb1 = (const float*)d_in[10];
    const float* nw2 = (const float*)d_in[11];
    const float* nb2 = (const float*)d_in[12];
    const float* lng = (const float*)d_in[13];
    const float* lnb = (const float*)d_in[14];
    const float* rw1 = (const float*)d_in[15];
    const float* rb1 = (const float*)d_in[16];
    const float* rw2 = (const float*)d_in[17];
    const float* rb2 = (const float*)d_in[18];
    float* out = (float*)d_out;

    float* h      = (float*)d_ws;                            // 4 MB
    u16*   xb0    = (u16*)(h + (size_t)BN * HIDD);           // 2 MB
    u16*   xb1    = xb0 + (size_t)BN * HIDD;                 // 2 MB
    u16*   aggb   = xb1 + (size_t)BN * HIDD;                 // 2 MB
    u16*   lutall = aggb + (size_t)BN * HIDD;                // 2 MB (interleaved)
    u16*   liwT   = lutall + (size_t)NBLK * TLUT * 256;      // 128 KB
    u16*   nw1T   = liwT + (size_t)NBLK * HIDD * HIDD;
    u16*   nw2T   = nw1T + (size_t)NBLK * HIDD * HIDD;
    u16*   ro1T   = nw2T + (size_t)NBLK * HIDD * HIDD;       // 16 KB
    int*   cnt    = (int*)(ro1T + 64 * HIDD);                // 32 KB
    int2*  meta   = (int2*)(cnt + BN);                       // 8 MB

    k_prep<<<256, 256, 0, stream>>>(liw, nw1, nw2, rw1, liwT, nw1T, nw2T, ro1T,
                                    cnt, out, out_size);
    k_edges<<<EE / 256, 256, 0, stream>>>(ei, pos, cnt, meta);
    k_lutall<<<NBLK * (TLUT / 32), 256, 0, stream>>>(ew1, eb1, ew2, eb2, lutall);
    k_embedx<<<BN / MROWS, 256, 0, stream>>>(Z, ew, liwT, h, xb0);

    u16* xbuf[2] = {xb0, xb1};
    for (int i = 0; i < NBLK; ++i) {
        int last = (i == NBLK - 1);
        k_agg<<<BN / 4, 256, 0, stream>>>(cnt, meta, lutall + (size_t)i * TLUT * 256,
                                          xbuf[i & 1], aggb);
        k_mlp<<<BN / MROWS, 256, 0, stream>>>(
            aggb, h,
            nw1T + (size_t)i * HIDD * HIDD, nb1 + i * HIDD,
            nw2T + (size_t)i * HIDD * HIDD, nb2 + i * HIDD,
            lng + i * HIDD, lnb + i * HIDD,
            last ? ro1T : liwT + (size_t)(i + 1) * HIDD * HIDD,
            last ? (u16*)nullptr : xbuf[(i + 1) & 1],
            last, rb1, rw2, rb2, out);
    }
}